// Round 2
// baseline (729.005 us; speedup 1.0000x reference)
//
#include <hip/hip_runtime.h>
#include <stdint.h>

// ---------------- problem constants ----------------
#define NODES   20001
#define EMB     128
#define HID     256
#define BROWS   8192
#define NWORLD  16

// ---------------- GEMM tiling ----------------
#define BM 128
#define BN 128
#define NTILES ((NODES + BN - 1) / BN)    // 157
#define MAXMT  (BROWS / BM + NWORLD)      // 80

// ---------------- workspace layout (bytes) ----------------
#define WS_H    0                          // bf16 h [8192][256] = 4 MB
#define WS_SORT (4194304)                  // int sorted_rows[10240]
#define WS_CNT  (WS_SORT + 10240 * 4)      // int counts[16]
#define WS_CUR  (WS_CNT + 64)              // int cursors[16]
#define WS_PFX  (WS_CUR + 64)              // int pprefix[16]
#define WS_MTW  (WS_PFX + 64)              // int mt_world[80]
#define WS_MTB  (WS_MTW + 320)             // int mt_base[80]
#define WS_MTV  (WS_MTB + 320)             // int mt_valid[80]
#define WS_NMT  (WS_MTV + 320)             // int n_mtiles
#define WS_CTRL_BYTES (WS_NMT + 4 - WS_SORT)

// ---------------- types ----------------
typedef __attribute__((ext_vector_type(8))) short          s8v;
typedef __attribute__((ext_vector_type(8))) unsigned short us8v;
typedef __attribute__((ext_vector_type(8))) __bf16         b8v;
typedef __attribute__((ext_vector_type(4))) float          f4v;

struct ABArg {
  us8v u;
  __device__ operator us8v() const { return u; }
  __device__ operator s8v()  const { return __builtin_bit_cast(s8v, u); }
  __device__ operator b8v()  const { return __builtin_bit_cast(b8v, u); }
};

static __device__ __forceinline__ f4v mfma16x16x32(us8v a, us8v b, f4v c) {
  return __builtin_amdgcn_mfma_f32_16x16x32_bf16(ABArg{a}, ABArg{b}, c, 0, 0, 0);
}

// f32 -> bf16 round-to-nearest-even
static __device__ __forceinline__ unsigned short f2b(float f) {
  unsigned u = __builtin_bit_cast(unsigned, f);
  u += 0x7FFFu + ((u >> 16) & 1u);
  return (unsigned short)(u >> 16);
}

static __device__ __forceinline__ us8v pack8(float4 a, float4 b) {
  us8v r;
  r[0] = f2b(a.x); r[1] = f2b(a.y); r[2] = f2b(a.z); r[3] = f2b(a.w);
  r[4] = f2b(b.x); r[5] = f2b(b.y); r[6] = f2b(b.z); r[7] = f2b(b.w);
  return r;
}

// ---------------- bucketing kernels ----------------
__global__ void k_hist(const int* __restrict__ ctx, int* __restrict__ counts) {
  int i = blockIdx.x * 256 + threadIdx.x;
  int w = ctx[i] - 1;
  w = w < 0 ? 0 : (w > 15 ? 15 : w);
  atomicAdd(&counts[w], 1);
}

__global__ void k_plan(const int* __restrict__ counts, int* __restrict__ pfx,
                       int* __restrict__ mtw, int* __restrict__ mtb,
                       int* __restrict__ mtv, int* __restrict__ nmt) {
  if (threadIdx.x != 0 || blockIdx.x != 0) return;
  int pbase = 0, total = 0;
  for (int w = 0; w < NWORLD; ++w) {
    int c = counts[w];
    pfx[w] = pbase;
    int tiles = (c + BM - 1) / BM;
    for (int t = 0; t < tiles; ++t) {
      mtw[total] = w;
      mtb[total] = pbase + t * BM;
      int v = c - t * BM;
      mtv[total] = v > BM ? BM : v;
      ++total;
    }
    pbase += tiles * BM;
  }
  *nmt = total;
}

__global__ void k_scatter(const int* __restrict__ ctx, const int* __restrict__ pfx,
                          int* __restrict__ cur, int* __restrict__ sorted) {
  int i = blockIdx.x * 256 + threadIdx.x;
  int w = ctx[i] - 1;
  w = w < 0 ? 0 : (w > 15 ? 15 : w);
  int pos = pfx[w] + atomicAdd(&cur[w], 1);
  sorted[pos] = i;
}

// ---------------- MLP (h = relu(relu(x W1^T + b1) W2^T + b2), bf16 out) ----------------
template <bool SWZOUT>
static __device__ __forceinline__ void mlp_layer(const unsigned short* aLds,
                                                 unsigned short* oLds,
                                                 const float* __restrict__ W,
                                                 const float* __restrict__ bias,
                                                 int lane, int j0) {
  f4v acc[4][4];
  const f4v fzero = {0.f, 0.f, 0.f, 0.f};
  for (int mf = 0; mf < 4; ++mf)
    for (int nf = 0; nf < 4; ++nf) acc[mf][nf] = fzero;

  for (int ks = 0; ks < 8; ++ks) {
    int kk = ks * 32 + ((lane >> 4) << 3);
    int cc = kk >> 3;
    us8v a[4], b[4];
    for (int nf = 0; nf < 4; ++nf) {
      int j = j0 + nf * 16 + (lane & 15);
      const float* wp = W + (size_t)j * 256 + kk;
      float4 u0 = *(const float4*)wp;
      float4 u1 = *(const float4*)(wp + 4);
      b[nf] = pack8(u0, u1);
    }
    for (int mf = 0; mf < 4; ++mf) {
      int row = mf * 16 + (lane & 15);
      a[mf] = *(const us8v*)((const char*)aLds + row * 512 + ((cc ^ (row & 7)) << 4));
    }
    for (int mf = 0; mf < 4; ++mf)
      for (int nf = 0; nf < 4; ++nf)
        acc[mf][nf] = mfma16x16x32(a[mf], b[nf], acc[mf][nf]);
  }

  for (int nf = 0; nf < 4; ++nf) {
    int j = j0 + nf * 16 + (lane & 15);
    float bv = bias[j];
    for (int mf = 0; mf < 4; ++mf) {
      for (int r = 0; r < 4; ++r) {
        int m = mf * 16 + ((lane >> 4) << 2) + r;
        float v = acc[mf][nf][r] + bv;
        v = v > 0.f ? v : 0.f;
        unsigned short hv = f2b(v);
        if (SWZOUT) {
          int byteoff = m * 512 + ((((j >> 3) ^ (m & 7))) << 4) + (j & 7) * 2;
          *(unsigned short*)((char*)oLds + byteoff) = hv;
        } else {
          *(unsigned short*)((char*)oLds + m * 512 + j * 2) = hv;
        }
      }
    }
  }
}

__global__ __launch_bounds__(256, 2) void k_mlp(
    const int* __restrict__ source, const int* __restrict__ mode,
    const float* __restrict__ se, const float* __restrict__ me,
    const float* __restrict__ W1, const float* __restrict__ b1,
    const float* __restrict__ W2, const float* __restrict__ b2,
    unsigned short* __restrict__ hout) {
  __shared__ __align__(16) unsigned short xA[64 * 256];
  __shared__ __align__(16) unsigned short h1A[64 * 256];
  const int tid = threadIdx.x;
  const int lane = tid & 63;
  const int wid = tid >> 6;
  const int r0 = blockIdx.x * 64;

  {
    int rl = tid >> 2, part = tid & 3;
    int row = r0 + rl;
    const float* src = (part < 2) ? (se + (size_t)source[row] * EMB + part * 64)
                                  : (me + (size_t)mode[row] * EMB + (part - 2) * 64);
    for (int i = 0; i < 16; ++i) {
      float4 v = ((const float4*)src)[i];
      int c = part * 8 + (i >> 1);
      int byteoff = rl * 512 + ((c ^ (rl & 7)) << 4) + (i & 1) * 8;
      ushort4 bb;
      bb.x = f2b(v.x); bb.y = f2b(v.y); bb.z = f2b(v.z); bb.w = f2b(v.w);
      *(ushort4*)((char*)xA + byteoff) = bb;
    }
  }
  __syncthreads();

  const int j0 = wid * 64;
  mlp_layer<true>(xA, h1A, W1, b1, lane, j0);
  __syncthreads();
  mlp_layer<false>(h1A, xA, W2, b2, lane, j0);
  __syncthreads();

  {
    int rl = tid >> 2, part = tid & 3;
    const uint4* s = (const uint4*)((const char*)xA + rl * 512 + part * 128);
    uint4* d = (uint4*)((char*)(hout + (size_t)(r0 + rl) * 256) + part * 128);
    for (int i = 0; i < 8; ++i) d[i] = s[i];
  }
}

// ---------------- big head GEMM ----------------
// A (h rows, bf16) read directly from global (L2-resident, 4 MB).
// B (headsW f32) reg-staged + packed to bf16, double-buffered swizzled LDS.
// Epilogue: LDS-transposed full-row contiguous stores.
__global__ __launch_bounds__(256, 4) void k_gemm(
    const unsigned short* __restrict__ h, const int* __restrict__ sorted,
    const int* __restrict__ mtw, const int* __restrict__ mtb,
    const int* __restrict__ mtv, const int* __restrict__ nmt,
    const float* __restrict__ headsW, const float* __restrict__ headsb,
    float* __restrict__ out) {
  const int y = blockIdx.y;
  if (y >= *nmt) return;
  const int w = mtw[y];
  const int base = mtb[y];
  const int vcnt = mtv[y];

  // bijective XCD chunk swizzle over the 157 n-tiles (q=19, r=5)
  const int Lx = blockIdx.x;
  const int cch = Lx & 7, jch = Lx >> 3;
  const int xw = (cch < 5) ? (cch * 20 + jch) : (100 + (cch - 5) * 19 + jch);
  const int n0 = xw * BN;

  __shared__ __align__(16) union {
    unsigned short Bs[2][BN * 64];   // 32 KB (two k-tile buffers)
    float stage[64 * 132];           // 33.8 KB epilogue staging
  } su;
  __shared__ int rlArr[BM];

  const int tid = threadIdx.x;
  const int lane = tid & 63;
  const int wid = tid >> 6;
  const int wr = wid >> 1, wc = wid & 1;

  if (tid < BM) rlArr[tid] = sorted[base + tid];

  // B staging assignment: thread -> (node row 0..127, 4 chunks of 16B)
  const int srow = tid >> 1;
  const int cbase = (tid & 1) * 4;
  const size_t hb = (size_t)w * NODES;
  int ng = n0 + srow;
  ng = ng < NODES ? ng : NODES - 1;
  const float* bsrc = headsW + (hb + (size_t)ng) * 256;

  f4v acc[4][4];
  {
    const f4v fzero = {0.f, 0.f, 0.f, 0.f};
    for (int mf = 0; mf < 4; ++mf)
      for (int nf = 0; nf < 4; ++nf) acc[mf][nf] = fzero;
  }

  // prologue: stage B k-tile 0 into buffer 0 (packed bf16, swizzled)
  for (int q = 0; q < 4; ++q) {
    int c = cbase + q;
    int cs = c ^ (srow & 7);
    float4 f0 = *(const float4*)(bsrc + c * 8);
    float4 f1 = *(const float4*)(bsrc + c * 8 + 4);
    *(us8v*)((char*)su.Bs[0] + srow * 128 + cs * 16) = pack8(f0, f1);
  }
  __syncthreads();

  // per-wave A row pointers (read directly from global h)
  const int klane = (lane >> 4) << 3;
  const unsigned short* aptr[4];
  for (int mf = 0; mf < 4; ++mf) {
    int rowm = wr * 64 + mf * 16 + (lane & 15);
    aptr[mf] = h + (size_t)rlArr[rowm] * 256 + klane;
  }

  int buf = 0;
  for (int ks = 0; ks < 4; ++ks) {
    // prefetch next B k-tile into regs, packed immediately (16 VGPR live)
    us8v bnp[4];
    const bool pf = ks < 3;
    if (pf) {
      int ko = (ks + 1) * 64;
      for (int q = 0; q < 4; ++q) {
        int c = cbase + q;
        float4 f0 = *(const float4*)(bsrc + ko + c * 8);
        float4 f1 = *(const float4*)(bsrc + ko + c * 8 + 4);
        bnp[q] = pack8(f0, f1);
      }
    }

    // A fragments for this k-step, issued early (L2 hits)
    us8v a[8];
    for (int h2 = 0; h2 < 2; ++h2)
      for (int mf = 0; mf < 4; ++mf)
        a[h2 * 4 + mf] = *(const us8v*)(aptr[mf] + ks * 64 + h2 * 32);

    // compute current buffer
    const char* Bb = (const char*)su.Bs[buf];
    for (int h2 = 0; h2 < 2; ++h2) {
      int cc = h2 * 4 + (lane >> 4);
      us8v b[4];
      for (int nf = 0; nf < 4; ++nf) {
        int node = wc * 64 + nf * 16 + (lane & 15);
        b[nf] = *(const us8v*)(Bb + node * 128 + ((cc ^ (node & 7)) << 4));
      }
      for (int mf = 0; mf < 4; ++mf)
        for (int nf = 0; nf < 4; ++nf)
          acc[mf][nf] = mfma16x16x32(a[h2 * 4 + mf], b[nf], acc[mf][nf]);
    }

    // write staged regs into the other buffer
    if (pf) {
      char* Bd = (char*)su.Bs[buf ^ 1];
      for (int q = 0; q < 4; ++q) {
        int c = cbase + q;
        int cs = c ^ (srow & 7);
        *(us8v*)(Bd + srow * 128 + cs * 16) = bnp[q];
      }
    }
    __syncthreads();
    buf ^= 1;
  }

  // bias per nf column (guarded)
  float hbias[4];
  for (int nf = 0; nf < 4; ++nf) {
    int n = n0 + wc * 64 + nf * 16 + (lane & 15);
    hbias[nf] = (n < NODES) ? headsb[hb + n] : 0.f;
  }

  // epilogue: two passes of 64 rows through padded LDS stage, then
  // full-row contiguous dword stores (4x 128B bursts per row, one wave).
  const bool fullN = (n0 + BN) <= NODES;
  for (int p = 0; p < 2; ++p) {
    if (wr == p) {
      for (int mf = 0; mf < 4; ++mf)
        for (int nf = 0; nf < 4; ++nf)
          for (int r = 0; r < 4; ++r) {
            int rloc = mf * 16 + ((lane >> 4) << 2) + r;
            int col = wc * 64 + nf * 16 + (lane & 15);
            su.stage[rloc * 132 + col] = acc[mf][nf][r] + hbias[nf];
          }
    }
    __syncthreads();
    {
      int lane32 = tid & 31;
      for (int j = 0; j < 8; ++j) {
        int rloc = j * 8 + (tid >> 5);
        int m = p * 64 + rloc;
        if (m < vcnt) {
          int rowg = rlArr[m];
          float4 v = *(const float4*)&su.stage[rloc * 132 + lane32 * 4];
          size_t ob = (size_t)rowg * NODES + n0 + lane32 * 4;
          if (fullN) {
            out[ob + 0] = v.x; out[ob + 1] = v.y;
            out[ob + 2] = v.z; out[ob + 3] = v.w;
          } else {
            int n = n0 + lane32 * 4;
            if (n + 0 < NODES) out[ob + 0] = v.x;
            if (n + 1 < NODES) out[ob + 1] = v.y;
            if (n + 2 < NODES) out[ob + 2] = v.z;
            if (n + 3 < NODES) out[ob + 3] = v.w;
          }
        }
      }
    }
    if (p == 0) __syncthreads();
  }
}

// ---------------- launcher ----------------
extern "C" void kernel_launch(void* const* d_in, const int* in_sizes, int n_in,
                              void* d_out, int out_size, void* d_ws, size_t ws_size,
                              hipStream_t stream) {
  const int* source   = (const int*)d_in[0];
  const int* mode     = (const int*)d_in[1];
  const int* ctx      = (const int*)d_in[2];
  const float* se     = (const float*)d_in[3];
  const float* me     = (const float*)d_in[4];
  const float* W1     = (const float*)d_in[5];
  const float* b1     = (const float*)d_in[6];
  const float* W2     = (const float*)d_in[7];
  const float* b2     = (const float*)d_in[8];
  const float* headsW = (const float*)d_in[9];
  const float* headsb = (const float*)d_in[10];
  float* out = (float*)d_out;
  char* ws = (char*)d_ws;

  unsigned short* hbuf = (unsigned short*)(ws + WS_H);
  int* sorted = (int*)(ws + WS_SORT);
  int* counts = (int*)(ws + WS_CNT);
  int* cur    = (int*)(ws + WS_CUR);
  int* pfx    = (int*)(ws + WS_PFX);
  int* mtw    = (int*)(ws + WS_MTW);
  int* mtb    = (int*)(ws + WS_MTB);
  int* mtv    = (int*)(ws + WS_MTV);
  int* nmt    = (int*)(ws + WS_NMT);

  hipMemsetAsync(ws + WS_SORT, 0, WS_CTRL_BYTES, stream);

  k_hist<<<BROWS / 256, 256, 0, stream>>>(ctx, counts);
  k_plan<<<1, 64, 0, stream>>>(counts, pfx, mtw, mtb, mtv, nmt);
  k_scatter<<<BROWS / 256, 256, 0, stream>>>(ctx, pfx, cur, sorted);
  k_mlp<<<BROWS / 64, 256, 0, stream>>>(source, mode, se, me, W1, b1, W2, b2, hbuf);
  k_gemm<<<dim3(NTILES, MAXMT), 256, 0, stream>>>(hbuf, sorted, mtw, mtb, mtv, nmt,
                                                  headsW, headsb, out);
}

// Round 3
// 571.026 us; speedup vs baseline: 1.2767x; 1.2767x over previous
//
#include <hip/hip_runtime.h>
#include <stdint.h>

// ---------------- problem constants ----------------
#define NODES   20001
#define EMB     128
#define HID     256
#define BROWS   8192
#define NWORLD  16

// ---------------- GEMM tiling ----------------
#define BM 128
#define BN 128
#define CHN 1280                           // nodes per block strip (10 sub-tiles)
#define CHUNKS 16                          // 16*1280 = 20480 >= 20001
#define MAXMT  (BROWS / BM + NWORLD)       // 80

// ---------------- workspace layout (bytes) ----------------
#define WS_H    0                          // bf16 h [8192][256] = 4 MB
#define WS_SORT (4194304)                  // int sorted_rows[10240]
#define WS_CNT  (WS_SORT + 10240 * 4)      // int counts[16]
#define WS_CUR  (WS_CNT + 64)              // int cursors[16]
#define WS_PFX  (WS_CUR + 64)              // int pprefix[16]
#define WS_MTW  (WS_PFX + 64)              // int mt_world[80]
#define WS_MTB  (WS_MTW + 320)             // int mt_base[80]
#define WS_MTV  (WS_MTB + 320)             // int mt_valid[80]
#define WS_NMT  (WS_MTV + 320)             // int n_mtiles
#define WS_CTRL_BYTES (WS_NMT + 4 - WS_SORT)

// ---------------- types ----------------
typedef __attribute__((ext_vector_type(8))) short          s8v;
typedef __attribute__((ext_vector_type(8))) unsigned short us8v;
typedef __attribute__((ext_vector_type(8))) __bf16         b8v;
typedef __attribute__((ext_vector_type(4))) float          f4v;

struct ABArg {
  us8v u;
  __device__ operator us8v() const { return u; }
  __device__ operator s8v()  const { return __builtin_bit_cast(s8v, u); }
  __device__ operator b8v()  const { return __builtin_bit_cast(b8v, u); }
};

static __device__ __forceinline__ f4v mfma16x16x32(us8v a, us8v b, f4v c) {
  return __builtin_amdgcn_mfma_f32_16x16x32_bf16(ABArg{a}, ABArg{b}, c, 0, 0, 0);
}

// f32 -> bf16 round-to-nearest-even
static __device__ __forceinline__ unsigned short f2b(float f) {
  unsigned u = __builtin_bit_cast(unsigned, f);
  u += 0x7FFFu + ((u >> 16) & 1u);
  return (unsigned short)(u >> 16);
}

static __device__ __forceinline__ us8v pack8(float4 a, float4 b) {
  us8v r;
  r[0] = f2b(a.x); r[1] = f2b(a.y); r[2] = f2b(a.z); r[3] = f2b(a.w);
  r[4] = f2b(b.x); r[5] = f2b(b.y); r[6] = f2b(b.z); r[7] = f2b(b.w);
  return r;
}

// ---------------- bucketing kernels ----------------
__global__ void k_hist(const int* __restrict__ ctx, int* __restrict__ counts) {
  int i = blockIdx.x * 256 + threadIdx.x;
  int w = ctx[i] - 1;
  w = w < 0 ? 0 : (w > 15 ? 15 : w);
  atomicAdd(&counts[w], 1);
}

__global__ void k_plan(const int* __restrict__ counts, int* __restrict__ pfx,
                       int* __restrict__ mtw, int* __restrict__ mtb,
                       int* __restrict__ mtv, int* __restrict__ nmt) {
  if (threadIdx.x != 0 || blockIdx.x != 0) return;
  int pbase = 0, total = 0;
  for (int w = 0; w < NWORLD; ++w) {
    int c = counts[w];
    pfx[w] = pbase;
    int tiles = (c + BM - 1) / BM;
    for (int t = 0; t < tiles; ++t) {
      mtw[total] = w;
      mtb[total] = pbase + t * BM;
      int v = c - t * BM;
      mtv[total] = v > BM ? BM : v;
      ++total;
    }
    pbase += tiles * BM;
  }
  *nmt = total;
}

__global__ void k_scatter(const int* __restrict__ ctx, const int* __restrict__ pfx,
                          int* __restrict__ cur, int* __restrict__ sorted) {
  int i = blockIdx.x * 256 + threadIdx.x;
  int w = ctx[i] - 1;
  w = w < 0 ? 0 : (w > 15 ? 15 : w);
  int pos = pfx[w] + atomicAdd(&cur[w], 1);
  sorted[pos] = i;
}

// ---------------- MLP (h = relu(relu(x W1^T + b1) W2^T + b2), bf16 out) ----------------
template <bool SWZOUT>
static __device__ __forceinline__ void mlp_layer(const unsigned short* aLds,
                                                 unsigned short* oLds,
                                                 const float* __restrict__ W,
                                                 const float* __restrict__ bias,
                                                 int lane, int j0) {
  f4v acc[4][4];
  const f4v fzero = {0.f, 0.f, 0.f, 0.f};
  for (int mf = 0; mf < 4; ++mf)
    for (int nf = 0; nf < 4; ++nf) acc[mf][nf] = fzero;

  for (int ks = 0; ks < 8; ++ks) {
    int kk = ks * 32 + ((lane >> 4) << 3);
    int cc = kk >> 3;
    us8v a[4], b[4];
    for (int nf = 0; nf < 4; ++nf) {
      int j = j0 + nf * 16 + (lane & 15);
      const float* wp = W + (size_t)j * 256 + kk;
      float4 u0 = *(const float4*)wp;
      float4 u1 = *(const float4*)(wp + 4);
      b[nf] = pack8(u0, u1);
    }
    for (int mf = 0; mf < 4; ++mf) {
      int row = mf * 16 + (lane & 15);
      a[mf] = *(const us8v*)((const char*)aLds + row * 512 + ((cc ^ (row & 7)) << 4));
    }
    for (int mf = 0; mf < 4; ++mf)
      for (int nf = 0; nf < 4; ++nf)
        acc[mf][nf] = mfma16x16x32(a[mf], b[nf], acc[mf][nf]);
  }

  for (int nf = 0; nf < 4; ++nf) {
    int j = j0 + nf * 16 + (lane & 15);
    float bv = bias[j];
    for (int mf = 0; mf < 4; ++mf) {
      for (int r = 0; r < 4; ++r) {
        int m = mf * 16 + ((lane >> 4) << 2) + r;
        float v = acc[mf][nf][r] + bv;
        v = v > 0.f ? v : 0.f;
        unsigned short hv = f2b(v);
        if (SWZOUT) {
          int byteoff = m * 512 + ((((j >> 3) ^ (m & 7))) << 4) + (j & 7) * 2;
          *(unsigned short*)((char*)oLds + byteoff) = hv;
        } else {
          *(unsigned short*)((char*)oLds + m * 512 + j * 2) = hv;
        }
      }
    }
  }
}

__global__ __launch_bounds__(256, 2) void k_mlp(
    const int* __restrict__ source, const int* __restrict__ mode,
    const float* __restrict__ se, const float* __restrict__ me,
    const float* __restrict__ W1, const float* __restrict__ b1,
    const float* __restrict__ W2, const float* __restrict__ b2,
    unsigned short* __restrict__ hout) {
  __shared__ __align__(16) unsigned short xA[64 * 256];
  __shared__ __align__(16) unsigned short h1A[64 * 256];
  const int tid = threadIdx.x;
  const int lane = tid & 63;
  const int wid = tid >> 6;
  const int r0 = blockIdx.x * 64;

  {
    int rl = tid >> 2, part = tid & 3;
    int row = r0 + rl;
    const float* src = (part < 2) ? (se + (size_t)source[row] * EMB + part * 64)
                                  : (me + (size_t)mode[row] * EMB + (part - 2) * 64);
    for (int i = 0; i < 16; ++i) {
      float4 v = ((const float4*)src)[i];
      int c = part * 8 + (i >> 1);
      int byteoff = rl * 512 + ((c ^ (rl & 7)) << 4) + (i & 1) * 8;
      ushort4 bb;
      bb.x = f2b(v.x); bb.y = f2b(v.y); bb.z = f2b(v.z); bb.w = f2b(v.w);
      *(ushort4*)((char*)xA + byteoff) = bb;
    }
  }
  __syncthreads();

  const int j0 = wid * 64;
  mlp_layer<true>(xA, h1A, W1, b1, lane, j0);
  __syncthreads();
  mlp_layer<false>(h1A, xA, W2, b2, lane, j0);
  __syncthreads();

  {
    int rl = tid >> 2, part = tid & 3;
    const uint4* s = (const uint4*)((const char*)xA + rl * 512 + part * 128);
    uint4* d = (uint4*)((char*)(hout + (size_t)(r0 + rl) * 256) + part * 128);
    for (int i = 0; i < 8; ++i) d[i] = s[i];
  }
}

// ---------------- big head GEMM (strip version) ----------------
// One block = one mtile (128 sorted rows) x one 1280-node strip.
// 10 n-sub-tiles processed sequentially; B double-buffer never drains
// across sub-tiles; per-row writes become 10 back-to-back 512B segments
// (straddle lines merge in L2 -> ~no write amplification).
__global__ __launch_bounds__(256, 2) void k_gemm(
    const unsigned short* __restrict__ h, const int* __restrict__ sorted,
    const int* __restrict__ mtw, const int* __restrict__ mtb,
    const int* __restrict__ mtv, const int* __restrict__ nmt,
    const float* __restrict__ headsW, const float* __restrict__ headsb,
    float* __restrict__ out) {
  const int y = blockIdx.y;
  if (y >= *nmt) return;
  const int w = mtw[y];
  const int base = mtb[y];
  const int vcnt = mtv[y];
  const int chunk = blockIdx.x;
  const int cn0 = chunk * CHN;
  const int NT = min(10, (NODES - cn0 + 127) >> 7);

  __shared__ __align__(16) unsigned short Bs[2][BN * 64];  // 32 KB
  __shared__ __align__(16) float stage[64 * 136];          // 34.8 KB
  __shared__ int rlArr[BM];

  const int tid = threadIdx.x;
  const int lane = tid & 63;
  const int wid = tid >> 6;
  const int wr = wid >> 1, wc = wid & 1;

  if (tid < BM) rlArr[tid] = sorted[base + tid];
  __syncthreads();

  // B staging decomposition: thread -> chunk sc (0..7), rows sr0+32r (r=0..3)
  // wave reads 2KB fully contiguous per load-pair (coalesced streaming).
  const int sc = tid & 7;
  const int sr0 = tid >> 3;
  const size_t hb = (size_t)w * NODES;

  // per-wave A row pointers (bf16 h read directly from global; L2-resident)
  const int klane = (lane >> 4) << 3;
  const unsigned short* aptr[4];
  for (int mf = 0; mf < 4; ++mf) {
    int rowm = wr * 64 + mf * 16 + (lane & 15);
    aptr[mf] = h + (size_t)rlArr[rowm] * 256 + klane;
  }

  // prologue: stage (t=0, k0) into Bs[0]
  for (int r = 0; r < 4; ++r) {
    int row = sr0 + 32 * r;
    int ng = cn0 + row; ng = ng < NODES ? ng : NODES - 1;
    const float* p = headsW + (hb + (size_t)ng) * 256 + sc * 8;
    float4 f0 = ((const float4*)p)[0];
    float4 f1 = ((const float4*)p)[1];
    *(us8v*)((char*)Bs[0] + row * 128 + ((sc ^ (row & 7)) << 4)) = pack8(f0, f1);
  }
  __syncthreads();

  int buf = 0;
  for (int t = 0; t < NT; ++t) {
    f4v acc[4][4];
    {
      const f4v fzero = {0.f, 0.f, 0.f, 0.f};
      for (int mf = 0; mf < 4; ++mf)
        for (int nf = 0; nf < 4; ++nf) acc[mf][nf] = fzero;
    }

    for (int ks = 0; ks < 4; ++ks) {
      const bool pf = !(t == NT - 1 && ks == 3);
      float4 pf0[4], pf1[4];
      if (pf) {
        const int tn = (ks < 3) ? t : t + 1;
        const int kon = (ks < 3) ? (ks + 1) * 64 : 0;
        const int n0n = cn0 + tn * 128;
        for (int r = 0; r < 4; ++r) {
          int row = sr0 + 32 * r;
          int ng = n0n + row; ng = ng < NODES ? ng : NODES - 1;
          const float* p = headsW + (hb + (size_t)ng) * 256 + kon + sc * 8;
          pf0[r] = ((const float4*)p)[0];
          pf1[r] = ((const float4*)p)[1];
        }
      }

      // A fragments for this k-step (issued early; L2 hits)
      us8v a[8];
      for (int h2 = 0; h2 < 2; ++h2)
        for (int mf = 0; mf < 4; ++mf)
          a[h2 * 4 + mf] = *(const us8v*)(aptr[mf] + ks * 64 + h2 * 32);

      // compute from current buffer
      const char* Bb = (const char*)Bs[buf];
      for (int h2 = 0; h2 < 2; ++h2) {
        int cc = h2 * 4 + (lane >> 4);
        us8v b[4];
        for (int nf = 0; nf < 4; ++nf) {
          int node = wc * 64 + nf * 16 + (lane & 15);
          b[nf] = *(const us8v*)(Bb + node * 128 + ((cc ^ (node & 7)) << 4));
        }
        for (int mf = 0; mf < 4; ++mf)
          for (int nf = 0; nf < 4; ++nf)
            acc[mf][nf] = mfma16x16x32(a[h2 * 4 + mf], b[nf], acc[mf][nf]);
      }

      // pack + write prefetched k-tile into the other buffer
      if (pf) {
        char* Bd = (char*)Bs[buf ^ 1];
        for (int r = 0; r < 4; ++r) {
          int row = sr0 + 32 * r;
          *(us8v*)(Bd + row * 128 + ((sc ^ (row & 7)) << 4)) = pack8(pf0[r], pf1[r]);
        }
      }
      __syncthreads();
      buf ^= 1;
    }

    // ---- epilogue for sub-tile t ----
    const int n0 = cn0 + t * 128;
    const bool fullN = (n0 + BN) <= NODES;
    float hbias[4];
    for (int nf = 0; nf < 4; ++nf) {
      int n = n0 + wc * 64 + nf * 16 + (lane & 15);
      hbias[nf] = (n < NODES) ? headsb[hb + n] : 0.f;
    }

    for (int p = 0; p < 2; ++p) {
      if (p) __syncthreads();  // protect stage from previous pass readers
      if (wr == p) {
        for (int mf = 0; mf < 4; ++mf)
          for (int nf = 0; nf < 4; ++nf)
            for (int r = 0; r < 4; ++r) {
              int rloc = mf * 16 + ((lane >> 4) << 2) + r;
              int col = wc * 64 + nf * 16 + (lane & 15);
              stage[rloc * 136 + col] = acc[mf][nf][r] + hbias[nf];
            }
      }
      __syncthreads();
      {
        int lane32 = tid & 31;
        for (int j = 0; j < 8; ++j) {
          int rloc = j * 8 + (tid >> 5);
          int m = p * 64 + rloc;
          if (m < vcnt) {
            int rowg = rlArr[m];
            float4 v = *(const float4*)&stage[rloc * 136 + lane32 * 4];
            size_t ob = (size_t)rowg * NODES + n0 + lane32 * 4;
            if (fullN) {
              out[ob + 0] = v.x; out[ob + 1] = v.y;
              out[ob + 2] = v.z; out[ob + 3] = v.w;
            } else {
              int n = n0 + lane32 * 4;
              if (n + 0 < NODES) out[ob + 0] = v.x;
              if (n + 1 < NODES) out[ob + 1] = v.y;
              if (n + 2 < NODES) out[ob + 2] = v.z;
              if (n + 3 < NODES) out[ob + 3] = v.w;
            }
          }
        }
      }
    }
    // stage reuse next tile is separated by 4 k-step barriers -> safe
  }
}

// ---------------- launcher ----------------
extern "C" void kernel_launch(void* const* d_in, const int* in_sizes, int n_in,
                              void* d_out, int out_size, void* d_ws, size_t ws_size,
                              hipStream_t stream) {
  const int* source   = (const int*)d_in[0];
  const int* mode     = (const int*)d_in[1];
  const int* ctx      = (const int*)d_in[2];
  const float* se     = (const float*)d_in[3];
  const float* me     = (const float*)d_in[4];
  const float* W1     = (const float*)d_in[5];
  const float* b1     = (const float*)d_in[6];
  const float* W2     = (const float*)d_in[7];
  const float* b2     = (const float*)d_in[8];
  const float* headsW = (const float*)d_in[9];
  const float* headsb = (const float*)d_in[10];
  float* out = (float*)d_out;
  char* ws = (char*)d_ws;

  unsigned short* hbuf = (unsigned short*)(ws + WS_H);
  int* sorted = (int*)(ws + WS_SORT);
  int* counts = (int*)(ws + WS_CNT);
  int* cur    = (int*)(ws + WS_CUR);
  int* pfx    = (int*)(ws + WS_PFX);
  int* mtw    = (int*)(ws + WS_MTW);
  int* mtb    = (int*)(ws + WS_MTB);
  int* mtv    = (int*)(ws + WS_MTV);
  int* nmt    = (int*)(ws + WS_NMT);

  hipMemsetAsync(ws + WS_SORT, 0, WS_CTRL_BYTES, stream);

  k_hist<<<BROWS / 256, 256, 0, stream>>>(ctx, counts);
  k_plan<<<1, 64, 0, stream>>>(counts, pfx, mtw, mtb, mtv, nmt);
  k_scatter<<<BROWS / 256, 256, 0, stream>>>(ctx, pfx, cur, sorted);
  k_mlp<<<BROWS / 64, 256, 0, stream>>>(source, mode, se, me, W1, b1, W2, b2, hbuf);
  k_gemm<<<dim3(CHUNKS, MAXMT), 256, 0, stream>>>(hbuf, sorted, mtw, mtb, mtv, nmt,
                                                  headsW, headsb, out);
}